// Round 4
// baseline (211.468 us; speedup 1.0000x reference)
//
#include <hip/hip_runtime.h>
#include <stdint.h>

// VQ-VAE quantization: B=131072 rows of z (D=64) vs N_E=1024 codes.
// Outputs (flat f32): z_q [131072*64] | loss [1] | idx [131072] | var(idx,ddof=1) [1]
//
// R4: split for ablation + code-stationary compute.
//  K0 vq_prep: codebook -> -2e bf16 MFMA A-frags + ||e||^2+0.5 (unchanged).
//  K1 vq_dist: 1024-thr blocks (16 waves); each wave keeps 4 code tiles (64
//     codes) STATIONARY in registers; streams z coalesced; packed-key argmin;
//     16-way cross-wave combine via LDS atomicMin; writes key+zz per row to ws.
//  K2 vq_out: pure memory kernel: gather z_q, write idx, loss/var partials.
//  K3 vq_final: scalar reduce.
// key = (float_bits(0.5+||e||^2-2z.e) & ~1023) | n ; unsigned min == argmin.

typedef __attribute__((ext_vector_type(8))) __bf16 bf16x8;
typedef __attribute__((ext_vector_type(4))) float f32x4;

#define OUT_LOSS 8388608
#define OUT_IDX  8388609
#define OUT_VAR  8519681

// workspace layout (bytes)
#define WS_LOSS  0                 // float[2048] per-block loss partials
#define WS_S1    8192              // int[2048] sum(idx)
#define WS_S2    16384             // int[2048] sum(idx^2)
#define WS_EFRAG 24576             // bf16x8[64 tiles * 2 ksteps * 64 lanes] = 131072 B
#define WS_EE    (24576 + 131072)  // float[1024] ||e_n||^2 + 0.5
#define WS_KEY   (WS_EE + 4096)    // unsigned[131072] packed argmin keys
#define WS_ZZ    (WS_KEY + 524288) // float[131072] ||z_row||^2

// ---- K0: prep codebook fragments -----------------------------------------
__global__ void vq_prep(const float* __restrict__ emb, char* __restrict__ ws) {
  bf16x8* efrag = (bf16x8*)(ws + WS_EFRAG);
  float* eeoff = (float*)(ws + WS_EE);
  const int t = blockIdx.x;    // tile 0..63
  const int l = threadIdx.x;   // 0..63
  const int n = t * 16 + (l & 15);
  const int kb0 = (l >> 4) * 8;
  const float* er = emb + n * 64;
  for (int j = 0; j < 2; ++j) {
    const int kb = j * 32 + kb0;
    bf16x8 h;
#pragma unroll
    for (int i = 0; i < 8; ++i) h[i] = (__bf16)(-2.0f * er[kb + i]);
    efrag[(t * 2 + j) * 64 + l] = h;
  }
  if (l < 16) {
    const float* e2 = emb + (t * 16 + l) * 64;
    float s = 0.f;
#pragma unroll
    for (int d = 0; d < 64; ++d) s += e2[d] * e2[d];
    eeoff[t * 16 + l] = s + 0.5f;
  }
}

// ---- K1: distances + argmin only ------------------------------------------
// 1024 blocks x 1024 threads; block handles 2 row-tiles of 64 rows.
// Wave w owns code tiles w*4..w*4+3, held in registers for the whole kernel.
__global__ void __launch_bounds__(1024, 4) vq_dist(
    const float* __restrict__ z, char* __restrict__ ws) {
  const int tid = threadIdx.x;
  const int wave = tid >> 6, lane = tid & 63;
  const int lr = lane & 15, ksl = lane >> 4;
  const int k0 = ksl * 8;

  __shared__ unsigned skey[64];
  __shared__ float szz[64];

  // stationary codes: 4 tiles x (e0,e1,ee) = 48 VGPR
  const bf16x8* efrag = (const bf16x8*)(ws + WS_EFRAG);
  const f32x4* eeoff = (const f32x4*)(ws + WS_EE);
  bf16x8 e0b[4], e1b[4];
  f32x4 eeb[4];
#pragma unroll
  for (int tt = 0; tt < 4; ++tt) {
    const int t = wave * 4 + tt;
    e0b[tt] = efrag[(t * 2 + 0) * 64 + lane];
    e1b[tt] = efrag[(t * 2 + 1) * 64 + lane];
    eeb[tt] = eeoff[t * 4 + ksl];
  }

  unsigned* wskey = (unsigned*)(ws + WS_KEY);
  float* wszz = (float*)(ws + WS_ZZ);

  for (int s = 0; s < 2; ++s) {
    const int row_base = (blockIdx.x * 2 + s) * 64;
    if (tid < 64) skey[tid] = 0xFFFFFFFFu;
    __syncthreads();

    // load + convert this row-tile's B-fragments (all 16 waves load the same
    // 16 KB; first wave misses, rest hit L1). zz computed by wave 0 only.
    bf16x8 zf[4][2];
    float zz[4];
#pragma unroll
    for (int r = 0; r < 4; ++r) {
      const float* zr = z + (size_t)(row_base + r * 16 + lr) * 64;
      float acc = 0.f;
#pragma unroll
      for (int j = 0; j < 2; ++j) {
        f32x4 v0 = *(const f32x4*)(zr + j * 32 + k0);
        f32x4 v1 = *(const f32x4*)(zr + j * 32 + k0 + 4);
        bf16x8 h;
#pragma unroll
        for (int i = 0; i < 4; ++i) {
          h[i] = (__bf16)v0[i]; h[4 + i] = (__bf16)v1[i];
          if (wave == 0) acc += v0[i] * v0[i] + v1[i] * v1[i];
        }
        zf[r][j] = h;
      }
      zz[r] = acc;
    }

    unsigned mkey[4];
#pragma unroll
    for (int r = 0; r < 4; ++r) mkey[r] = 0xFFFFFFFFu;

#pragma unroll
    for (int tt = 0; tt < 4; ++tt) {
      const unsigned nb = (unsigned)((wave * 4 + tt) * 16 + ksl * 4);
#pragma unroll
      for (int r = 0; r < 4; ++r) {
        f32x4 a = __builtin_amdgcn_mfma_f32_16x16x32_bf16(e0b[tt], zf[r][0], eeb[tt], 0, 0, 0);
        a = __builtin_amdgcn_mfma_f32_16x16x32_bf16(e1b[tt], zf[r][1], a, 0, 0, 0);
        // packed keys; nested mins -> v_min3_u32 matchable
        const unsigned key0 = (__float_as_uint(a[0]) & 0xFFFFFC00u) | (nb + 0);
        const unsigned key1 = (__float_as_uint(a[1]) & 0xFFFFFC00u) | (nb + 1);
        const unsigned key2 = (__float_as_uint(a[2]) & 0xFFFFFC00u) | (nb + 2);
        const unsigned key3 = (__float_as_uint(a[3]) & 0xFFFFFC00u) | (nb + 3);
        mkey[r] = min(min(min(key0, key1), key2), min(key3, mkey[r]));
      }
    }

    // reduce over k-slot lane groups, then 16-way cross-wave via LDS atomicMin
#pragma unroll
    for (int r = 0; r < 4; ++r) {
      mkey[r] = min(mkey[r], (unsigned)__shfl_xor((int)mkey[r], 16, 64));
      mkey[r] = min(mkey[r], (unsigned)__shfl_xor((int)mkey[r], 32, 64));
      if (ksl == 0) atomicMin(&skey[r * 16 + lr], mkey[r]);
    }
    if (wave == 0) {
#pragma unroll
      for (int r = 0; r < 4; ++r) {
        zz[r] += __shfl_xor(zz[r], 16, 64);
        zz[r] += __shfl_xor(zz[r], 32, 64);
        if (ksl == 0) szz[r * 16 + lr] = zz[r];
      }
    }
    __syncthreads();
    if (tid < 64) {
      wskey[row_base + tid] = skey[tid];
      wszz[row_base + tid] = szz[tid];
    }
    __syncthreads();   // protect skey reinit next iteration
  }
}

// ---- K2: gather/output kernel (pure memory) --------------------------------
// 2048 blocks x 256 threads; 64 rows/block, 4 threads per row.
__global__ void __launch_bounds__(256) vq_out(
    const float* __restrict__ emb, float* __restrict__ out,
    char* __restrict__ ws) {
  const int tid = threadIdx.x;
  const int wave = tid >> 6, lane = tid & 63;
  const int row_base = blockIdx.x * 64;
  const int row = tid >> 2, seg = tid & 3;

  const unsigned* wskey = (const unsigned*)(ws + WS_KEY);
  const float* wszz = (const float*)(ws + WS_ZZ);

  const unsigned k = wskey[row_base + row];
  const unsigned idx = k & 1023u;
  const size_t rowg = (size_t)row_base + row;
  const f32x4* ep = (const f32x4*)(emb + (size_t)idx * 64 + seg * 16);
  f32x4* op = (f32x4*)(out + rowg * 64 + seg * 16);
#pragma unroll
  for (int c = 0; c < 4; ++c) op[c] = ep[c];

  float ls = 0.f; int s1 = 0, s2 = 0;
  if (seg == 0) {
    ls = wszz[row_base + row] + __uint_as_float(k & 0xFFFFFC00u) - 0.5f;
    s1 = (int)idx;
    s2 = (int)(idx * idx);
    out[OUT_IDX + rowg] = (float)idx;
  }
#pragma unroll
  for (int off = 1; off < 64; off <<= 1) {
    ls += __shfl_xor(ls, off, 64);
    s1 += __shfl_xor(s1, off, 64);
    s2 += __shfl_xor(s2, off, 64);
  }
  __shared__ float sL[4];
  __shared__ int sA[4], sB[4];
  if (lane == 0) { sL[wave] = ls; sA[wave] = s1; sB[wave] = s2; }
  __syncthreads();
  if (tid == 0) {
    float L = 0; int a = 0, b = 0;
#pragma unroll
    for (int w = 0; w < 4; ++w) { L += sL[w]; a += sA[w]; b += sB[w]; }
    ((float*)(ws + WS_LOSS))[blockIdx.x] = L;
    ((int*)(ws + WS_S1))[blockIdx.x] = a;
    ((int*)(ws + WS_S2))[blockIdx.x] = b;
  }
}

// ---- K3: final scalar reduce over 2048 block partials ---------------------
__global__ void vq_final(float* __restrict__ out, const char* __restrict__ ws) {
  const int t = threadIdx.x;   // 256 threads
  const float* lp = (const float*)(ws + WS_LOSS);
  const int* p1 = (const int*)(ws + WS_S1);
  const int* p2 = (const int*)(ws + WS_S2);
  double L = 0; long long a = 0, b = 0;
#pragma unroll
  for (int kk = 0; kk < 8; ++kk) {
    const int i = t + 256 * kk;
    L += (double)lp[i];
    a += (long long)p1[i];
    b += (long long)p2[i];
  }
#pragma unroll
  for (int off = 1; off < 64; off <<= 1) {
    L += __shfl_xor(L, off, 64);
    a += __shfl_xor(a, off, 64);
    b += __shfl_xor(b, off, 64);
  }
  __shared__ double sL[4];
  __shared__ long long sA[4], sB[4];
  const int wave = t >> 6, lane = t & 63;
  if (lane == 0) { sL[wave] = L; sA[wave] = a; sB[wave] = b; }
  __syncthreads();
  if (t == 0) {
    double Lt = 0; long long at = 0, bt = 0;
#pragma unroll
    for (int w = 0; w < 4; ++w) { Lt += sL[w]; at += sA[w]; bt += sB[w]; }
    // loss = (beta + 1) * mean((z_q - z)^2), beta = 0.25
    out[OUT_LOSS] = (float)(1.25 * Lt / 8388608.0);
    // var(idx, ddof=1) exact: (n*S2 - S1^2) / (n*(n-1))
    long long num = bt * 131072LL - at * at;
    out[OUT_VAR] = (float)((double)num / (131072.0 * 131071.0));
  }
}

extern "C" void kernel_launch(void* const* d_in, const int* in_sizes, int n_in,
                              void* d_out, int out_size, void* d_ws, size_t ws_size,
                              hipStream_t stream) {
  (void)in_sizes; (void)n_in; (void)out_size; (void)ws_size;
  const float* z = (const float*)d_in[0];
  const float* emb = (const float*)d_in[1];
  float* out = (float*)d_out;
  char* ws = (char*)d_ws;
  vq_prep<<<64, 64, 0, stream>>>(emb, ws);
  vq_dist<<<1024, 1024, 0, stream>>>(z, ws);
  vq_out<<<2048, 256, 0, stream>>>(emb, out, ws);
  vq_final<<<1, 256, 0, stream>>>(out, ws);
}

// Round 5
// 87.365 us; speedup vs baseline: 2.4205x; 2.4205x over previous
//
#include <hip/hip_runtime.h>
#include <stdint.h>

// VQ-VAE quantization: B=131072 rows of z (D=64) vs N_E=1024 codes.
// Outputs (flat f32): z_q [131072*64] | loss [1] | idx [131072] | var(idx,ddof=1) [1]
//
// R5: code-stationary, spill-free, barrier-free.
//  K0 vq_prep: codebook -> -2e bf16 MFMA A-frags + ||e||^2+0.5.
//  K1 vq_dist: 2048 blocks x 512 thr (8 waves). Wave w holds code tiles
//     w*8..w*8+7 (128 codes) STATIONARY in 64 VGPRs; loops 4x16 z-rows.
//     Per-wave packed-key argmin written to ws (no cross-wave sync at all).
//  K2 vq_out: per row, min over the 8 per-wave keys -> idx; gather z_q;
//     loss/var partials.  K3 vq_final: scalar reduce.
// key = (float_bits(0.5+||e||^2-2z.e) & ~1023) | code ; unsigned min == argmin;
// in-tile index (4 bits) OR'd first, tile*16 added after the per-tile min
// (bits 4..9 are zero, so no carry into value bits).

typedef __attribute__((ext_vector_type(8))) __bf16 bf16x8;
typedef __attribute__((ext_vector_type(4))) float f32x4;

#define OUT_LOSS 8388608
#define OUT_IDX  8388609
#define OUT_VAR  8519681

// workspace layout (bytes); total ~4.9 MB
#define WS_LOSS  0                  // float[2048] per-block loss partials
#define WS_S1    8192               // int[2048] sum(idx)
#define WS_S2    16384              // int[2048] sum(idx^2)
#define WS_EFRAG 24576              // bf16x8[64 tiles * 2 ksteps * 64 lanes] = 128 KB
#define WS_EE    155648             // float[1024] ||e||^2 + 0.5 (4 KB)
#define WS_KEY   159744             // unsigned[131072][8] per-wave keys (4 MB)
#define WS_ZZ    4354048            // float[131072] ||z_row||^2 (512 KB)

// ---- K0: prep codebook fragments -----------------------------------------
// A-frag for mfma_f32_16x16x32_bf16: lane l holds code row (t*16 + (l&15)),
// k = kstep*32 + (l>>4)*8 + i. Values are -2*e.
__global__ void vq_prep(const float* __restrict__ emb, char* __restrict__ ws) {
  bf16x8* efrag = (bf16x8*)(ws + WS_EFRAG);
  float* eeoff = (float*)(ws + WS_EE);
  const int t = blockIdx.x;    // tile 0..63
  const int l = threadIdx.x;   // 0..63
  const int n = t * 16 + (l & 15);
  const int kb0 = (l >> 4) * 8;
  const float* er = emb + n * 64;
  for (int j = 0; j < 2; ++j) {
    const int kb = j * 32 + kb0;
    bf16x8 h;
#pragma unroll
    for (int i = 0; i < 8; ++i) h[i] = (__bf16)(-2.0f * er[kb + i]);
    efrag[(t * 2 + j) * 64 + l] = h;
  }
  if (l < 16) {
    const float* e2 = emb + (t * 16 + l) * 64;
    float s = 0.f;
#pragma unroll
    for (int d = 0; d < 64; ++d) s += e2[d] * e2[d];
    eeoff[t * 16 + l] = s + 0.5f;
  }
}

// ---- K1: distances + per-wave argmin (no barriers, no LDS) -----------------
__global__ void __launch_bounds__(512, 4) vq_dist(
    const float* __restrict__ z, char* __restrict__ ws) {
  const int tid = threadIdx.x;
  const int wave = tid >> 6, lane = tid & 63;
  const int lr = lane & 15, ksl = lane >> 4;
  const int k0 = ksl * 8;

  const bf16x8* efrag = (const bf16x8*)(ws + WS_EFRAG);
  const f32x4* eeoff4 = (const f32x4*)(ws + WS_EE);
  unsigned* wkey = (unsigned*)(ws + WS_KEY);
  float* wzz = (float*)(ws + WS_ZZ);

  // stationary codes: 8 tiles x (e0,e1) = 64 VGPR; ee reloaded per use (L1-hot)
  bf16x8 e0b[8], e1b[8];
#pragma unroll
  for (int tt = 0; tt < 8; ++tt) {
    const int t = wave * 8 + tt;
    e0b[tt] = efrag[(t * 2 + 0) * 64 + lane];
    e1b[tt] = efrag[(t * 2 + 1) * 64 + lane];
  }
  const unsigned k4 = (unsigned)(ksl * 4);   // in-tile index bits 0..3

  for (int it = 0; it < 4; ++it) {
    const int row_base = blockIdx.x * 64 + it * 16;
    // z subtile: lane -> row lr, this ksl's 16 dims; same for all 8 waves (L1)
    const float* zr = z + (size_t)(row_base + lr) * 64;
    f32x4 v0 = *(const f32x4*)(zr + k0);
    f32x4 v1 = *(const f32x4*)(zr + k0 + 4);
    f32x4 v2 = *(const f32x4*)(zr + 32 + k0);
    f32x4 v3 = *(const f32x4*)(zr + 32 + k0 + 4);
    bf16x8 zf0, zf1;
#pragma unroll
    for (int i = 0; i < 4; ++i) {
      zf0[i] = (__bf16)v0[i]; zf0[4 + i] = (__bf16)v1[i];
      zf1[i] = (__bf16)v2[i]; zf1[4 + i] = (__bf16)v3[i];
    }
    if (wave == 0) {   // ||z_row||^2 for the loss; wave-uniform branch
      float s = 0.f;
#pragma unroll
      for (int i = 0; i < 4; ++i)
        s += v0[i] * v0[i] + v1[i] * v1[i] + v2[i] * v2[i] + v3[i] * v3[i];
      s += __shfl_xor(s, 16, 64);
      s += __shfl_xor(s, 32, 64);
      if (ksl == 0) wzz[row_base + lr] = s;
    }

    unsigned rkey = 0xFFFFFFFFu;
#pragma unroll
    for (int tt = 0; tt < 8; ++tt) {
      const int t = wave * 8 + tt;
      f32x4 a = __builtin_amdgcn_mfma_f32_16x16x32_bf16(e0b[tt], zf0, eeoff4[t * 4 + ksl], 0, 0, 0);
      a = __builtin_amdgcn_mfma_f32_16x16x32_bf16(e1b[tt], zf1, a, 0, 0, 0);
      // per-tile min with 4-bit in-tile index, then fold tile id into bits 4..9
      const unsigned t0 = (__float_as_uint(a[0]) & 0xFFFFFC00u) | (k4 + 0);
      const unsigned t1 = (__float_as_uint(a[1]) & 0xFFFFFC00u) | (k4 + 1);
      const unsigned t2 = (__float_as_uint(a[2]) & 0xFFFFFC00u) | (k4 + 2);
      const unsigned t3 = (__float_as_uint(a[3]) & 0xFFFFFC00u) | (k4 + 3);
      const unsigned tk = min(min(t0, t1), min(t2, t3));
      rkey = min(rkey, tk + (unsigned)(t * 16));
    }
    // reduce across the 4 ksl groups (lanes with same lane&15 = same z-row)
    rkey = min(rkey, (unsigned)__shfl_xor((int)rkey, 16, 64));
    rkey = min(rkey, (unsigned)__shfl_xor((int)rkey, 32, 64));
    if (ksl == 0) wkey[(size_t)(row_base + lr) * 8 + wave] = rkey;
  }
}

// ---- K2: combine 8 per-wave keys, gather z_q, partials ---------------------
// 2048 blocks x 256 thr; 64 rows/block, 4 threads per row.
__global__ void __launch_bounds__(256) vq_out(
    const float* __restrict__ emb, float* __restrict__ out,
    char* __restrict__ ws) {
  const int tid = threadIdx.x;
  const int wave = tid >> 6, lane = tid & 63;
  const int row = tid >> 2, seg = tid & 3;
  const size_t rowg = (size_t)blockIdx.x * 64 + row;

  const unsigned* wkey = (const unsigned*)(ws + WS_KEY);
  const float* wzz = (const float*)(ws + WS_ZZ);

  unsigned k = 0xFFFFFFFFu;
  if (seg < 2) {
    const uint4 kk = ((const uint4*)(wkey + rowg * 8))[seg];
    k = min(min(kk.x, kk.y), min(kk.z, kk.w));
  }
  k = min(k, (unsigned)__shfl_xor((int)k, 1, 64));        // seg0<->seg1
  k = (unsigned)__shfl((int)k, (lane & 0x3C), 64);        // broadcast in row group
  const unsigned idx = k & 1023u;

  const f32x4* ep = (const f32x4*)(emb + (size_t)idx * 64 + seg * 16);
  f32x4* op = (f32x4*)(out + rowg * 64 + seg * 16);
#pragma unroll
  for (int c = 0; c < 4; ++c) op[c] = ep[c];

  float ls = 0.f; int s1 = 0, s2 = 0;
  if (seg == 0) {
    // d = ||z||^2 + (ee - 2 z.e)_min ; value has low 10 bits cleared
    ls = wzz[rowg] + __uint_as_float(k & 0xFFFFFC00u) - 0.5f;
    s1 = (int)idx;
    s2 = (int)(idx * idx);
    out[OUT_IDX + rowg] = (float)idx;
  }
#pragma unroll
  for (int off = 1; off < 64; off <<= 1) {
    ls += __shfl_xor(ls, off, 64);
    s1 += __shfl_xor(s1, off, 64);
    s2 += __shfl_xor(s2, off, 64);
  }
  __shared__ float sL[4];
  __shared__ int sA[4], sB[4];
  if (lane == 0) { sL[wave] = ls; sA[wave] = s1; sB[wave] = s2; }
  __syncthreads();
  if (tid == 0) {
    float L = 0; int a = 0, b = 0;
#pragma unroll
    for (int w = 0; w < 4; ++w) { L += sL[w]; a += sA[w]; b += sB[w]; }
    ((float*)(ws + WS_LOSS))[blockIdx.x] = L;
    ((int*)(ws + WS_S1))[blockIdx.x] = a;
    ((int*)(ws + WS_S2))[blockIdx.x] = b;
  }
}

// ---- K3: final scalar reduce over 2048 block partials ---------------------
__global__ void vq_final(float* __restrict__ out, const char* __restrict__ ws) {
  const int t = threadIdx.x;   // 256 threads
  const float* lp = (const float*)(ws + WS_LOSS);
  const int* p1 = (const int*)(ws + WS_S1);
  const int* p2 = (const int*)(ws + WS_S2);
  double L = 0; long long a = 0, b = 0;
#pragma unroll
  for (int kk = 0; kk < 8; ++kk) {
    const int i = t + 256 * kk;
    L += (double)lp[i];
    a += (long long)p1[i];
    b += (long long)p2[i];
  }
#pragma unroll
  for (int off = 1; off < 64; off <<= 1) {
    L += __shfl_xor(L, off, 64);
    a += __shfl_xor(a, off, 64);
    b += __shfl_xor(b, off, 64);
  }
  __shared__ double sL[4];
  __shared__ long long sA[4], sB[4];
  const int wave = t >> 6, lane = t & 63;
  if (lane == 0) { sL[wave] = L; sA[wave] = a; sB[wave] = b; }
  __syncthreads();
  if (t == 0) {
    double Lt = 0; long long at = 0, bt = 0;
#pragma unroll
    for (int w = 0; w < 4; ++w) { Lt += sL[w]; at += sA[w]; bt += sB[w]; }
    // loss = (beta + 1) * mean((z_q - z)^2), beta = 0.25
    out[OUT_LOSS] = (float)(1.25 * Lt / 8388608.0);
    // var(idx, ddof=1) exact: (n*S2 - S1^2) / (n*(n-1))
    long long num = bt * 131072LL - at * at;
    out[OUT_VAR] = (float)((double)num / (131072.0 * 131071.0));
  }
}

extern "C" void kernel_launch(void* const* d_in, const int* in_sizes, int n_in,
                              void* d_out, int out_size, void* d_ws, size_t ws_size,
                              hipStream_t stream) {
  (void)in_sizes; (void)n_in; (void)out_size; (void)ws_size;
  const float* z = (const float*)d_in[0];
  const float* emb = (const float*)d_in[1];
  float* out = (float*)d_out;
  char* ws = (char*)d_ws;
  vq_prep<<<64, 64, 0, stream>>>(emb, ws);
  vq_dist<<<2048, 512, 0, stream>>>(z, ws);
  vq_out<<<2048, 256, 0, stream>>>(emb, out, ws);
  vq_final<<<1, 256, 0, stream>>>(out, ws);
}